// Round 1
// baseline (165.827 us; speedup 1.0000x reference)
//
#include <hip/hip_runtime.h>
#include <hip/hip_bf16.h>

#define BATCH 16
#define CDIM 256
#define NDIM 2048
#define HDIM 128

typedef __bf16 bf16;
typedef float f32x4 __attribute__((ext_vector_type(4)));
typedef bf16 bf16x8 __attribute__((ext_vector_type(8)));

#define LOG2E 1.4426950408889634f

// Swizzled byte offsets for row-major bf16 LDS tiles.
// 512B rows (256 bf16 cols): XOR bits 4-7 with row&15 -> 16B-read conflict-free.
__device__ __forceinline__ int swz512(int row, int colbyte) {
  return row * 512 + (colbyte ^ ((row & 15) << 4));
}
// 256B rows (128 bf16 cols): XOR bits 4-6 with row&7.
__device__ __forceinline__ int swz256(int row, int colbyte) {
  return row * 256 + (colbyte ^ ((row & 7) << 4));
}

__device__ __forceinline__ f32x4 mfma16(bf16x8 a, bf16x8 b, f32x4 c) {
  return __builtin_amdgcn_mfma_f32_16x16x32_bf16(a, b, c, 0, 0, 0);
}

__device__ __forceinline__ bf16x8 cvt8(float4 a, float4 b) {
  bf16x8 o;
  o[0] = (bf16)a.x; o[1] = (bf16)a.y; o[2] = (bf16)a.z; o[3] = (bf16)a.w;
  o[4] = (bf16)b.x; o[5] = (bf16)b.y; o[6] = (bf16)b.z; o[7] = (bf16)b.w;
  return o;
}

// ---------------------------------------------------------------------------
// Kernel 1: fused QKV projection.
// grid 512 = (b:16) x (ntile:32, 64 cols each), 256 threads (4 waves).
// Q,K written [B][N][H] bf16 (n-major), V written [B][H][N] bf16.
// ---------------------------------------------------------------------------
__global__ __launch_bounds__(256) void k1_qkv(
    const float* __restrict__ x,
    const float* __restrict__ Wq, const float* __restrict__ bq,
    const float* __restrict__ Wk, const float* __restrict__ bk,
    const float* __restrict__ Wv, const float* __restrict__ bv,
    bf16* __restrict__ Qo, bf16* __restrict__ Ko, bf16* __restrict__ Vo) {
  __shared__ char lds[65536];
  char* xT = lds;            // [64 n][256 c] bf16, 512B rows, swz512 (32 KB)
  char* Wt = lds + 32768;    // [128 h][128 c-half] bf16, 256B rows, swz256 (32 KB)

  const int t = threadIdx.x;
  const int l = t & 63;
  const int w = t >> 6;
  const int b = blockIdx.x >> 5;
  const int n0 = (blockIdx.x & 31) * 64;

  // Stage x tile transposed: xT[n][c] <- x[b][c][n0+n], coalesced float4 reads.
#pragma unroll
  for (int pass = 0; pass < 16; ++pass) {
    int c = pass * 16 + (t >> 4);
    int nq = t & 15;
    const float4 v = *reinterpret_cast<const float4*>(
        x + (size_t)(b * CDIM + c) * NDIM + n0 + nq * 4);
    float fv[4] = {v.x, v.y, v.z, v.w};
#pragma unroll
    for (int i = 0; i < 4; ++i) {
      int row = nq * 4 + i;
      *reinterpret_cast<bf16*>(xT + swz512(row, c * 2)) = (bf16)fv[i];
    }
  }

  const float* Wp[3] = {Wq, Wk, Wv};
  const float* bp[3] = {bq, bk, bv};

#pragma unroll 1
  for (int p = 0; p < 3; ++p) {
    f32x4 acc[8];
#pragma unroll
    for (int i = 0; i < 8; ++i) acc[i] = f32x4{0.f, 0.f, 0.f, 0.f};

#pragma unroll 1
    for (int kh = 0; kh < 2; ++kh) {
      __syncthreads();  // prev compute done reading Wt (also covers xT staging)
      // Stage W K-half: Wt[h][c_local] <- W[h][kh*128 + c_local]
#pragma unroll
      for (int pass = 0; pass < 8; ++pass) {
        int h = pass * 16 + (t >> 4);
        int cq = t & 15;
        const float* src = Wp[p] + (size_t)h * CDIM + kh * 128 + cq * 8;
        float4 v0 = *reinterpret_cast<const float4*>(src);
        float4 v1 = *reinterpret_cast<const float4*>(src + 4);
        *reinterpret_cast<bf16x8*>(Wt + swz256(h, cq * 16)) = cvt8(v0, v1);
      }
      __syncthreads();

      if (p < 2) {
        // D[n][h] = xT * W^T : A rows = n (wave owns 16), B cols = h (8 frags)
#pragma unroll
        for (int ks = 0; ks < 4; ++ks) {
          int cb2 = ks * 64 + (l >> 4) * 16;
          bf16x8 a = *reinterpret_cast<const bf16x8*>(
              xT + swz512(w * 16 + (l & 15), kh * 256 + cb2));
#pragma unroll
          for (int nf = 0; nf < 8; ++nf) {
            bf16x8 bb = *reinterpret_cast<const bf16x8*>(
                Wt + swz256(nf * 16 + (l & 15), cb2));
            acc[nf] = mfma16(a, bb, acc[nf]);
          }
        }
      } else {
        // V: D[h][n] = W * x : A rows = h (wave owns 32), B cols = n (4 frags)
#pragma unroll
        for (int ks = 0; ks < 4; ++ks) {
          int cb2 = ks * 64 + (l >> 4) * 16;
          bf16x8 a0 = *reinterpret_cast<const bf16x8*>(
              Wt + swz256(w * 32 + (l & 15), cb2));
          bf16x8 a1 = *reinterpret_cast<const bf16x8*>(
              Wt + swz256(w * 32 + 16 + (l & 15), cb2));
#pragma unroll
          for (int nf = 0; nf < 4; ++nf) {
            bf16x8 bb = *reinterpret_cast<const bf16x8*>(
                xT + swz512(nf * 16 + (l & 15), kh * 256 + cb2));
            acc[nf] = mfma16(a0, bb, acc[nf]);
            acc[4 + nf] = mfma16(a1, bb, acc[4 + nf]);
          }
        }
      }
    }

    if (p < 2) {
      bf16* dst = (p == 0) ? Qo : Ko;
#pragma unroll
      for (int nf = 0; nf < 8; ++nf) {
        float bias = bp[p][nf * 16 + (l & 15)];
#pragma unroll
        for (int r = 0; r < 4; ++r) {
          int n = n0 + w * 16 + (l >> 4) * 4 + r;
          int h = nf * 16 + (l & 15);
          dst[(size_t)(b * NDIM + n) * HDIM + h] = (bf16)(acc[nf][r] + bias);
        }
      }
    } else {
#pragma unroll
      for (int mf = 0; mf < 2; ++mf)
#pragma unroll
        for (int nf = 0; nf < 4; ++nf)
#pragma unroll
          for (int r = 0; r < 4; ++r) {
            int h = w * 32 + mf * 16 + (l >> 4) * 4 + r;
            int n = n0 + nf * 16 + (l & 15);
            Vo[(size_t)(b * HDIM + h) * NDIM + n] =
                (bf16)(acc[mf * 4 + nf][r] + bp[2][h]);
          }
    }
  }
}

// ---------------------------------------------------------------------------
// Kernel 2: flash attention (no scale, per reference).
// grid 256 (XCD-swizzled: each XCD owns 2 batches), 512 threads (8 waves).
// Each block: 128 q-rows, iterate 16 K/V tiles of 128. O aliases Q buffer.
// ---------------------------------------------------------------------------
__global__ __launch_bounds__(512) void k2_attn(
    const bf16* __restrict__ Q, const bf16* __restrict__ K,
    const bf16* __restrict__ V, bf16* __restrict__ O) {
  __shared__ char lds[65536];
  char* KP = lds;            // [128][128] bf16 swz256: K tile, then P tile (32 KB)
  char* Vt = lds + 32768;    // [128 d][128 kpos] bf16 swz256 (32 KB)

  const int t = threadIdx.x;
  const int l = t & 63;
  const int w = t >> 6;
  // XCD-aware swizzle: HW round-robins blockIdx%8 across XCDs ->
  // give XCD x the 32 blocks of batches {2x, 2x+1} for K/V L2 locality.
  const int pid = blockIdx.x;
  const int xcd = pid & 7;
  const int slot = pid >> 3;  // 0..31
  const int b = xcd * 2 + (slot >> 4);
  const int q0 = (slot & 15) * 128;

  // Hoist Q fragments (wave owns q rows q0 + w*16 .. +15).
  bf16x8 qf[4];
  const bf16* qrow = Q + (size_t)(b * NDIM + q0 + w * 16 + (l & 15)) * HDIM;
#pragma unroll
  for (int ks = 0; ks < 4; ++ks)
    qf[ks] = *reinterpret_cast<const bf16x8*>(qrow + ks * 32 + (l >> 4) * 8);

  f32x4 of[8];
#pragma unroll
  for (int i = 0; i < 8; ++i) of[i] = f32x4{0.f, 0.f, 0.f, 0.f};
  float mrun[4], lsum[4];
#pragma unroll
  for (int r = 0; r < 4; ++r) { mrun[r] = -3.0e38f; lsum[r] = 0.f; }

#pragma unroll 1
  for (int kt = 0; kt < 16; ++kt) {
    const int kp0 = kt * 128;
    __syncthreads();  // previous PV done reading KP/Vt
    // Stage K tile: KP[kpos][d]
#pragma unroll
    for (int pass = 0; pass < 4; ++pass) {
      int krow = pass * 32 + (t >> 4);
      int hq = t & 15;
      uint4 d = *reinterpret_cast<const uint4*>(
          K + (size_t)(b * NDIM + kp0 + krow) * HDIM + hq * 8);
      *reinterpret_cast<uint4*>(KP + swz256(krow, hq * 16)) = d;
    }
    // Stage V tile transposed-by-layout: Vt[d][kpos] (V stored [B][H][N])
#pragma unroll
    for (int pass = 0; pass < 4; ++pass) {
      int drow = pass * 32 + (t >> 4);
      int cq = t & 15;
      uint4 d = *reinterpret_cast<const uint4*>(
          V + (size_t)(b * HDIM + drow) * NDIM + kp0 + cq * 8);
      *reinterpret_cast<uint4*>(Vt + swz256(drow, cq * 16)) = d;
    }
    __syncthreads();

    // S = Q K^T : D rows = q, cols = kpos
    f32x4 sf[8];
#pragma unroll
    for (int i = 0; i < 8; ++i) sf[i] = f32x4{0.f, 0.f, 0.f, 0.f};
#pragma unroll
    for (int ks = 0; ks < 4; ++ks) {
      int cb = ks * 64 + (l >> 4) * 16;
#pragma unroll
      for (int nf = 0; nf < 8; ++nf) {
        bf16x8 kb = *reinterpret_cast<const bf16x8*>(
            KP + swz256(nf * 16 + (l & 15), cb));
        sf[nf] = mfma16(qf[ks], kb, sf[nf]);
      }
    }

    // Online softmax: rows live in regs r (lane group l>>4 shares 4 rows).
    f32x4 mx = sf[0];
#pragma unroll
    for (int nf = 1; nf < 8; ++nf)
#pragma unroll
      for (int r = 0; r < 4; ++r) mx[r] = fmaxf(mx[r], sf[nf][r]);
#pragma unroll
    for (int off = 1; off < 16; off <<= 1)
#pragma unroll
      for (int r = 0; r < 4; ++r) mx[r] = fmaxf(mx[r], __shfl_xor(mx[r], off));

    float fac[4];
#pragma unroll
    for (int r = 0; r < 4; ++r) {
      float mnew = fmaxf(mrun[r], mx[r]);
      fac[r] = exp2f((mrun[r] - mnew) * LOG2E);
      mrun[r] = mnew;
    }
    f32x4 rs = f32x4{0.f, 0.f, 0.f, 0.f};
#pragma unroll
    for (int nf = 0; nf < 8; ++nf)
#pragma unroll
      for (int r = 0; r < 4; ++r) {
        float pv = exp2f((sf[nf][r] - mrun[r]) * LOG2E);
        sf[nf][r] = pv;
        rs[r] += pv;
      }
#pragma unroll
    for (int off = 1; off < 16; off <<= 1)
#pragma unroll
      for (int r = 0; r < 4; ++r) rs[r] += __shfl_xor(rs[r], off);
#pragma unroll
    for (int r = 0; r < 4; ++r) lsum[r] = lsum[r] * fac[r] + rs[r];
#pragma unroll
    for (int nf = 0; nf < 8; ++nf)
#pragma unroll
      for (int r = 0; r < 4; ++r) of[nf][r] *= fac[r];

    __syncthreads();  // all waves done reading KP as K
    // Write P (bf16) into KP
#pragma unroll
    for (int nf = 0; nf < 8; ++nf)
#pragma unroll
      for (int r = 0; r < 4; ++r) {
        int row = w * 16 + (l >> 4) * 4 + r;
        *reinterpret_cast<bf16*>(
            KP + swz256(row, (nf * 16 + (l & 15)) * 2)) = (bf16)sf[nf][r];
      }
    __syncthreads();

    // O += P V : A = P[q][kpos], B = V[kpos][d] read from Vt[d][kpos]
#pragma unroll
    for (int ks = 0; ks < 4; ++ks) {
      int cb = ks * 64 + (l >> 4) * 16;
      bf16x8 pa = *reinterpret_cast<const bf16x8*>(
          KP + swz256(w * 16 + (l & 15), cb));
#pragma unroll
      for (int nf = 0; nf < 8; ++nf) {
        bf16x8 vb = *reinterpret_cast<const bf16x8*>(
            Vt + swz256(nf * 16 + (l & 15), cb));
        of[nf] = mfma16(pa, vb, of[nf]);
      }
    }
  }

  // Normalize and write O [B][N][H] bf16 (aliases Q: same rows this wave read).
#pragma unroll
  for (int nf = 0; nf < 8; ++nf)
#pragma unroll
    for (int r = 0; r < 4; ++r) {
      int n = q0 + w * 16 + (l >> 4) * 4 + r;
      int h = nf * 16 + (l & 15);
      O[(size_t)(b * NDIM + n) * HDIM + h] = (bf16)(of[nf][r] / lsum[r]);
    }
}

// ---------------------------------------------------------------------------
// Kernel 3: out = Wf @ O + bf + x   (fp32 epilogue, fp32 output)
// grid 512 = (b:16) x (ntile:32, 64 cols), 256 threads (4 waves).
// ---------------------------------------------------------------------------
__global__ __launch_bounds__(256) void k3_proj(
    const bf16* __restrict__ O, const float* __restrict__ Wf,
    const float* __restrict__ bfv, const float* __restrict__ x,
    float* __restrict__ out) {
  __shared__ char lds[49152];
  char* Wt = lds;            // [128 c-half][128 h] bf16 swz256 (32 KB)
  char* Ot = lds + 32768;    // [64 n][128 h] bf16 swz256 (16 KB)

  const int t = threadIdx.x;
  const int l = t & 63;
  const int w = t >> 6;
  const int b = blockIdx.x >> 5;
  const int n0 = (blockIdx.x & 31) * 64;

  // Stage O tile once: Ot[n][h]
#pragma unroll
  for (int pass = 0; pass < 4; ++pass) {
    int n = pass * 16 + (t >> 4);
    int hq = t & 15;
    uint4 d = *reinterpret_cast<const uint4*>(
        O + (size_t)(b * NDIM + n0 + n) * HDIM + hq * 8);
    *reinterpret_cast<uint4*>(Ot + swz256(n, hq * 16)) = d;
  }

#pragma unroll 1
  for (int ch = 0; ch < 2; ++ch) {
    __syncthreads();
    // Stage Wf c-half: Wt[c_local][h]
#pragma unroll
    for (int pass = 0; pass < 8; ++pass) {
      int cl = pass * 16 + (t >> 4);
      int hq = t & 15;
      const float* src = Wf + (size_t)(ch * 128 + cl) * HDIM + hq * 8;
      float4 v0 = *reinterpret_cast<const float4*>(src);
      float4 v1 = *reinterpret_cast<const float4*>(src + 4);
      *reinterpret_cast<bf16x8*>(Wt + swz256(cl, hq * 16)) = cvt8(v0, v1);
    }
    __syncthreads();

    f32x4 acc[2][4];
#pragma unroll
    for (int i = 0; i < 2; ++i)
#pragma unroll
      for (int j = 0; j < 4; ++j) acc[i][j] = f32x4{0.f, 0.f, 0.f, 0.f};

#pragma unroll
    for (int ks = 0; ks < 4; ++ks) {
      int cb = ks * 64 + (l >> 4) * 16;
      bf16x8 a0 = *reinterpret_cast<const bf16x8*>(
          Wt + swz256(w * 32 + (l & 15), cb));
      bf16x8 a1 = *reinterpret_cast<const bf16x8*>(
          Wt + swz256(w * 32 + 16 + (l & 15), cb));
#pragma unroll
      for (int nf = 0; nf < 4; ++nf) {
        bf16x8 bb = *reinterpret_cast<const bf16x8*>(
            Ot + swz256(nf * 16 + (l & 15), cb));
        acc[0][nf] = mfma16(a0, bb, acc[0][nf]);
        acc[1][nf] = mfma16(a1, bb, acc[1][nf]);
      }
    }

#pragma unroll
    for (int mf = 0; mf < 2; ++mf)
#pragma unroll
      for (int nf = 0; nf < 4; ++nf)
#pragma unroll
        for (int r = 0; r < 4; ++r) {
          int c = ch * 128 + w * 32 + mf * 16 + (l >> 4) * 4 + r;
          int n = n0 + nf * 16 + (l & 15);
          size_t idx = (size_t)(b * CDIM + c) * NDIM + n;
          out[idx] = acc[mf][nf][r] + bfv[c] + x[idx];
        }
  }
}

extern "C" void kernel_launch(void* const* d_in, const int* in_sizes, int n_in,
                              void* d_out, int out_size, void* d_ws,
                              size_t ws_size, hipStream_t stream) {
  (void)in_sizes; (void)n_in; (void)out_size;
  const float* x = (const float*)d_in[0];
  const float* Wq = (const float*)d_in[1];
  const float* bq = (const float*)d_in[2];
  const float* Wk = (const float*)d_in[3];
  const float* bk = (const float*)d_in[4];
  const float* Wv = (const float*)d_in[5];
  const float* bv = (const float*)d_in[6];
  const float* Wf = (const float*)d_in[7];
  const float* bfv = (const float*)d_in[8];
  float* out = (float*)d_out;

  if (ws_size < (24u << 20)) return;  // need 24 MB scratch
  char* ws = (char*)d_ws;
  bf16* Qb = (bf16*)(ws);                  // 8 MB [B][N][H]; reused as O
  bf16* Kb = (bf16*)(ws + (8u << 20));     // 8 MB [B][N][H]
  bf16* Vb = (bf16*)(ws + (16u << 20));    // 8 MB [B][H][N]

  k1_qkv<<<512, 256, 0, stream>>>(x, Wq, bq, Wk, bk, Wv, bv, Qb, Kb, Vb);
  k2_attn<<<256, 512, 0, stream>>>(Qb, Kb, Vb, Qb);
  k3_proj<<<512, 256, 0, stream>>>(Qb, Wf, bfv, x, out);
}